// Round 1
// baseline (411.910 us; speedup 1.0000x reference)
//
#include <hip/hip_runtime.h>
#include <hip/hip_bf16.h>
#include <math.h>

// KAN layer: y = tanh(einsum('oic,bic->bo', coeffs, Bspline(x)) + silu(x)@Wb^T + rs*x)
// Strategy: features F[b, i*12+c] (11 spline slots + silu) in fp16, packed
// weights W[o, i*12+c] in fp16, fused MFMA GEMM with on-the-fly basis compute.

#define BATCH   16384
#define IN_DIM  512
#define OUT_DIM 512
#define NC      11
#define NK      15
#define FPI     12
#define KTOT    (IN_DIM * FPI)   // 6144

// ws layout (in floats): grid [512][20] | inv [512][48] | Wh (fp16) [512][6144]
#define WS_GRID_OFF 0
#define WS_INV_OFF  (IN_DIM * 20)
#define WS_WH_OFF   (IN_DIM * 20 + IN_DIM * 48)

typedef _Float16 half8 __attribute__((ext_vector_type(8)));
typedef float f32x4 __attribute__((ext_vector_type(4)));

// ---------------- kernel 1: knots + inverse denominators -------------------
__global__ void kan_prep(const float* __restrict__ gsl,    // [IN][NK-1]
                         const float* __restrict__ gstart, // [IN]
                         float* __restrict__ ws) {
    int i = blockIdx.x * blockDim.x + threadIdx.x;
    if (i >= IN_DIM) return;
    float t[18];
    float acc = gstart[i];
    t[0] = acc;
#pragma unroll
    for (int m = 0; m < NK - 1; ++m) {
        float z = gsl[i * (NK - 1) + m];
        // numerically stable softplus, matches jax.nn.softplus
        float sp = fmaxf(z, 0.f) + log1pf(__expf(-fabsf(z)));
        acc += sp;
        t[m + 1] = acc;
    }
    // pad knots so the local de Boor triangle never reads OOB (values unused)
    t[15] = t[14] + 1.f; t[16] = t[14] + 2.f; t[17] = t[14] + 3.f;
    float* g = ws + WS_GRID_OFF + i * 20;
#pragma unroll
    for (int m = 0; m < 18; ++m) g[m] = t[m];
    g[18] = 0.f; g[19] = 0.f;
    float* inv = ws + WS_INV_OFF + i * 48;
#pragma unroll
    for (int d = 1; d <= 3; ++d) {
#pragma unroll
        for (int jj = 0; jj < 16; ++jj) {
            float den = (jj + d <= 17) ? (t[jj + d] - t[jj]) : 1.f;
            inv[(d - 1) * 16 + jj] = (den == 0.f) ? 1.f : 1.f / den;  // ref: where(den==0,1,den)
        }
    }
}

// ---------------- kernel 2: pack [coeffs | base_weight] to fp16 ------------
__global__ void kan_packw(const float* __restrict__ coeffs, // [OUT][IN][NC]
                          const float* __restrict__ bw,     // [OUT][IN]
                          float* __restrict__ ws) {
    int idx = blockIdx.x * blockDim.x + threadIdx.x;
    if (idx >= OUT_DIM * IN_DIM) return;
    int o = idx >> 9, i = idx & 511;
    _Float16* Wh = (_Float16*)(ws + WS_WH_OFF);
    _Float16* dst = Wh + (size_t)o * KTOT + i * FPI;   // 24B, 8-aligned
    const float* src = coeffs + ((size_t)o * IN_DIM + i) * NC;
    union { _Float16 h[12]; float2 f2[3]; } u;
#pragma unroll
    for (int c = 0; c < NC; ++c) u.h[c] = (_Float16)src[c];
    u.h[11] = (_Float16)bw[(size_t)o * IN_DIM + i];
    float2* d2 = (float2*)dst;
    d2[0] = u.f2[0]; d2[1] = u.f2[1]; d2[2] = u.f2[2];
}

// ---------------- kernel 3: fused GEMM ------------------------------------
#define BM 128
#define BN 128
#define KI 8                 // input dims per K-step
#define KS (KI * FPI)        // 96 features per K-step
#define LDT 104              // padded LDS stride (halfs): 208B, 16B-aligned rows
#define NSTEP (IN_DIM / KI)  // 64

__launch_bounds__(256, 2)
__global__ void kan_main(const float* __restrict__ x,
                         const float* __restrict__ res_scale,
                         const float* __restrict__ ws_f,
                         float* __restrict__ out) {
    __shared__ __align__(16) _Float16 Al[BM][LDT];
    __shared__ __align__(16) _Float16 Bl[BN][LDT];
    __shared__ float lgrid[KI][20];
    __shared__ float linv[KI][48];

    const int tid = threadIdx.x;
    const int l = tid & 63;
    const int w = tid >> 6;
    const int ct = blockIdx.x & 3;   // col tile (OUT/BN = 4)
    const int rt = blockIdx.x >> 2;  // row tile
    const int b0 = rt * BM;
    const int o0 = ct * BN;

    const float* wsg = ws_f + WS_GRID_OFF;
    const float* wsi = ws_f + WS_INV_OFF;
    const _Float16* Wh = (const _Float16*)(ws_f + WS_WH_OFF);

    f32x4 acc[4][4];
    const f32x4 zz = {0.f, 0.f, 0.f, 0.f};
#pragma unroll
    for (int m = 0; m < 4; ++m)
#pragma unroll
        for (int n = 0; n < 4; ++n) acc[m][n] = zz;

    const int wr = (w >> 1) * 64;   // wave sub-tile origin (rows)
    const int wc = (w & 1) * 64;    // wave sub-tile origin (cols)

    for (int s = 0; s < NSTEP; ++s) {
        const int i0 = s * KI;
        __syncthreads();   // prev MFMA reads done; safe to overwrite LDS

        // stage grid + inv for this step's 8 input dims
        for (int idx = tid; idx < KI * 20; idx += 256)
            lgrid[idx / 20][idx % 20] = wsg[(size_t)(i0 + idx / 20) * 20 + idx % 20];
        for (int idx = tid; idx < KI * 48; idx += 256)
            linv[idx / 48][idx % 48] = wsi[(size_t)(i0 + idx / 48) * 48 + idx % 48];

        // stage B tile: 128 rows x 96 halfs from packed Wh
#pragma unroll
        for (int u6 = 0; u6 < 6; ++u6) {
            int idx = tid + u6 * 256;            // 0..1535 = 128*12
            int row = idx / 12, c16 = idx % 12;
            float4 v = *(const float4*)(Wh + (size_t)(o0 + row) * KTOT + (size_t)s * KS + c16 * 8);
            *(float4*)&Bl[row][c16 * 8] = v;
        }
        __syncthreads();   // lgrid/linv visible to everyone

        // A features: 128 rows x 8 input dims, one point per (thread, p)
#pragma unroll
        for (int p = 0; p < 4; ++p) {
            int pt = tid + p * 256;
            int row = pt >> 3;
            int il = pt & 7;
            float xv = x[(size_t)(b0 + row) * IN_DIM + i0 + il];
            const float* t = lgrid[il];
            float sil = xv / (1.f + __expf(-xv));   // silu
            union { _Float16 h[12]; float2 f2[3]; } u;
#pragma unroll
            for (int c = 0; c < 12; ++c) u.h[c] = (_Float16)0.f;
            u.h[11] = (_Float16)sil;
            _Float16* ap = &Al[row][il * FPI];
            ((float2*)ap)[0] = u.f2[0];
            ((float2*)ap)[1] = u.f2[1];
            ((float2*)ap)[2] = u.f2[2];

            // interval search (matches ref indicator convention)
            int j = 0;
#pragma unroll
            for (int m = 1; m <= 13; ++m) j += (xv >= t[m]) ? 1 : 0;
            bool valid = (xv >= t[0]) && (xv < t[14]);
            if (valid) {
                float left[4], right[4], N[4];
                N[0] = 1.f;
#pragma unroll
                for (int r = 1; r <= 3; ++r) {
                    int li = j + 1 - r; li = li < 0 ? 0 : li;
                    left[r] = xv - t[li];
                    right[r] = t[j + r] - xv;     // j+r <= 16, padded
                }
#pragma unroll
                for (int d = 1; d <= 3; ++d) {
                    float saved = 0.f;
#pragma unroll
                    for (int r = 0; r < d; ++r) {
                        int ii2 = j - d + 1 + r;
                        ii2 = ii2 < 0 ? 0 : (ii2 > 15 ? 15 : ii2);
                        float temp = N[r] * linv[il][(d - 1) * 16 + ii2];
                        N[r] = saved + right[r + 1] * temp;
                        saved = left[d - r] * temp;
                    }
                    N[d] = saved;
                }
                // scatter 4 nonzero basis values (truncate c>10 like the ref)
#pragma unroll
                for (int r = 0; r < 4; ++r) {
                    int c = j - 3 + r;
                    if (c >= 0 && c <= 10) ap[c] = (_Float16)N[r];
                }
            }
        }
        __syncthreads();   // A/B tiles ready

        // MFMA: wave computes 64x64 sub-tile = 4x4 frags of 16x16, K=96
        const int arow = wr + (l & 15);
        const int brow = wc + (l & 15);
        const int koff = (l >> 4) * 8;
#pragma unroll
        for (int kk = 0; kk < 3; ++kk) {
            half8 af[4], bf[4];
#pragma unroll
            for (int m = 0; m < 4; ++m)
                af[m] = *(const half8*)&Al[arow + m * 16][kk * 32 + koff];
#pragma unroll
            for (int n = 0; n < 4; ++n)
                bf[n] = *(const half8*)&Bl[brow + n * 16][kk * 32 + koff];
#pragma unroll
            for (int m = 0; m < 4; ++m)
#pragma unroll
                for (int n = 0; n < 4; ++n)
                    acc[m][n] = __builtin_amdgcn_mfma_f32_16x16x32_f16(af[m], bf[n], acc[m][n], 0, 0, 0);
        }
    }

    // epilogue: + rs*x, tanh, store. D map: col = l&15, row = (l>>4)*4 + reg
    const float rs = res_scale[0];
#pragma unroll
    for (int m = 0; m < 4; ++m) {
#pragma unroll
        for (int n = 0; n < 4; ++n) {
#pragma unroll
            for (int jj = 0; jj < 4; ++jj) {
                int r = b0 + wr + m * 16 + (l >> 4) * 4 + jj;
                int c = o0 + wc + n * 16 + (l & 15);
                float v = acc[m][n][jj] + rs * x[(size_t)r * IN_DIM + c];
                out[(size_t)r * OUT_DIM + c] = tanhf(v);
            }
        }
    }
}

extern "C" void kernel_launch(void* const* d_in, const int* in_sizes, int n_in,
                              void* d_out, int out_size, void* d_ws, size_t ws_size,
                              hipStream_t stream) {
    const float* x      = (const float*)d_in[0];
    const float* coeffs = (const float*)d_in[1];
    const float* bw     = (const float*)d_in[2];
    const float* gsl    = (const float*)d_in[3];
    const float* gstart = (const float*)d_in[4];
    const float* rs     = (const float*)d_in[5];
    float* out = (float*)d_out;
    float* ws  = (float*)d_ws;

    kan_prep<<<2, 256, 0, stream>>>(gsl, gstart, ws);
    kan_packw<<<(OUT_DIM * IN_DIM + 255) / 256, 256, 0, stream>>>(coeffs, bw, ws);
    kan_main<<<(BATCH / BM) * (OUT_DIM / BN), 256, 0, stream>>>(x, rs, ws, out);
}

// Round 2
// 323.417 us; speedup vs baseline: 1.2736x; 1.2736x over previous
//
#include <hip/hip_runtime.h>
#include <hip/hip_bf16.h>
#include <math.h>

// KAN layer, decoupled: (1) prep grid params, (2) pack weights fp16,
// (3) featurize x -> F[b, i*12+c] fp16 in ws, (4) m97-style MFMA GEMM
//     y = tanh(F @ W^T + rs*x)

#define IN_DIM  512
#define OUT_DIM 512
#define FPI     12
#define KTOT    (IN_DIM * FPI)    // 6144
#define NBATCH  16384

// ws layout: P (float, 56 slots x 512 dims, transposed for coalesced loads)
//          | Wh (fp16, 512 x 6144) | F (fp16, CH x 6144)
#define P_SLOTS     56
#define WS_WH_OFF_F (P_SLOTS * IN_DIM)
#define WS_F_OFF_B  ((size_t)(P_SLOTS * IN_DIM * 4) + (size_t)OUT_DIM * KTOT * 2)

typedef _Float16 half8 __attribute__((ext_vector_type(8)));
typedef float f32x4 __attribute__((ext_vector_type(4)));

__device__ __forceinline__ void gload16(const void* g, void* l) {
    __builtin_amdgcn_global_load_lds((const __attribute__((address_space(1))) void*)g,
                                     (__attribute__((address_space(3))) void*)l, 16, 0, 0);
}

// ---------------- kernel 1: knot positions + inverse denominators ----------
// P slots: t[0..14] -> 0..14 | inv1[0..13] -> 15..28 | inv2[0..12] -> 29..41
//          inv3[0..11] -> 42..53   (layout P[slot*512 + dim])
__global__ void kan_prep(const float* __restrict__ gsl, const float* __restrict__ gstart,
                         float* __restrict__ P) {
    int i = blockIdx.x * 256 + threadIdx.x;
    if (i >= IN_DIM) return;
    float t[15];
    float a = gstart[i];
    t[0] = a;
#pragma unroll
    for (int m = 0; m < 14; ++m) {
        float z = gsl[i * 14 + m];
        a += fmaxf(z, 0.f) + log1pf(__expf(-fabsf(z)));   // softplus, stable
        t[m + 1] = a;
    }
#pragma unroll
    for (int m = 0; m < 15; ++m) P[m * IN_DIM + i] = t[m];
#pragma unroll
    for (int m = 0; m < 14; ++m) { float d = t[m+1] - t[m]; P[(15+m)*IN_DIM + i] = 1.f / ((d == 0.f) ? 1.f : d); }
#pragma unroll
    for (int m = 0; m < 13; ++m) { float d = t[m+2] - t[m]; P[(29+m)*IN_DIM + i] = 1.f / ((d == 0.f) ? 1.f : d); }
#pragma unroll
    for (int m = 0; m < 12; ++m) { float d = t[m+3] - t[m]; P[(42+m)*IN_DIM + i] = 1.f / ((d == 0.f) ? 1.f : d); }
}

// ---------------- kernel 2: pack [coeffs | base_weight] to fp16 ------------
__global__ void kan_packw(const float* __restrict__ coeffs, const float* __restrict__ bw,
                          _Float16* __restrict__ Wh) {
    int idx = blockIdx.x * 256 + threadIdx.x;   // idx = o*512 + i, grid exactly covers
    const float* src = coeffs + (size_t)idx * 11;
    union { _Float16 h[12]; float2 f2[3]; } u;
#pragma unroll
    for (int c = 0; c < 11; ++c) u.h[c] = (_Float16)src[c];
    u.h[11] = (_Float16)bw[idx];
    float2* dst = (float2*)(Wh + (size_t)idx * FPI);
    dst[0] = u.f2[0]; dst[1] = u.f2[1]; dst[2] = u.f2[2];
}

// ---------------- kernel 3: featurize (dense Cox-de Boor, all in regs) -----
// thread = one input dim; params in registers; 32 rows per thread.
__launch_bounds__(256)
__global__ void kan_feat(const float* __restrict__ x, const float* __restrict__ P,
                         _Float16* __restrict__ F, int row0) {
    const int dim = (blockIdx.x & 1) * 256 + threadIdx.x;
    const int rb = blockIdx.x >> 1;
    float t[15], i1[14], i2[13], i3[12];
#pragma unroll
    for (int m = 0; m < 15; ++m) t[m]  = P[m * IN_DIM + dim];
#pragma unroll
    for (int m = 0; m < 14; ++m) i1[m] = P[(15 + m) * IN_DIM + dim];
#pragma unroll
    for (int m = 0; m < 13; ++m) i2[m] = P[(29 + m) * IN_DIM + dim];
#pragma unroll
    for (int m = 0; m < 12; ++m) i3[m] = P[(42 + m) * IN_DIM + dim];
    const int lr0 = rb * 32;
#pragma unroll 2
    for (int rr = 0; rr < 32; ++rr) {
        const int lr = lr0 + rr;
        const float xv = x[(size_t)(row0 + lr) * IN_DIM + dim];
        float d[15];
#pragma unroll
        for (int m = 0; m < 15; ++m) d[m] = xv - t[m];
        float b[14];
#pragma unroll
        for (int m = 0; m < 14; ++m) b[m] = (xv >= t[m] && xv < t[m + 1]) ? 1.f : 0.f;
#pragma unroll
        for (int m = 0; m < 13; ++m) b[m] = (d[m] * i1[m]) * b[m] + ((-d[m + 2]) * i1[m + 1]) * b[m + 1];
#pragma unroll
        for (int m = 0; m < 12; ++m) b[m] = (d[m] * i2[m]) * b[m] + ((-d[m + 3]) * i2[m + 1]) * b[m + 1];
#pragma unroll
        for (int m = 0; m < 11; ++m) b[m] = (d[m] * i3[m]) * b[m] + ((-d[m + 4]) * i3[m + 1]) * b[m + 1];
        const float sil = xv / (1.f + __expf(-xv));
        union { _Float16 h[12]; float2 f2[3]; } u;
#pragma unroll
        for (int c = 0; c < 11; ++c) u.h[c] = (_Float16)b[c];
        u.h[11] = (_Float16)sil;
        float2* dst = (float2*)(F + (size_t)lr * KTOT + dim * FPI);
        dst[0] = u.f2[0]; dst[1] = u.f2[1]; dst[2] = u.f2[2];
    }
}

// ---------------- kernel 4: GEMM (m97 structure) + fused epilogue ----------
__launch_bounds__(256, 2)
__global__ void kan_gemm(const _Float16* __restrict__ F, const _Float16* __restrict__ Wh,
                         const float* __restrict__ x, const float* __restrict__ rsp,
                         float* __restrict__ out, int row0) {
    __shared__ _Float16 As[128 * 32];
    __shared__ _Float16 Bs[128 * 32];
    int bid = blockIdx.x;
    const int nwg = gridDim.x;
    if ((nwg & 7) == 0) bid = (bid & 7) * (nwg >> 3) + (bid >> 3);  // XCD swizzle
    const int rt = bid >> 2, ct = bid & 3;
    const int lr0 = rt * 128, o0 = ct * 128;
    const int tid = threadIdx.x, l = tid & 63, w = tid >> 6;
    const int wr = (w >> 1) * 64, wc = (w & 1) * 64;

    f32x4 acc[4][4];
    const f32x4 zz = {0.f, 0.f, 0.f, 0.f};
#pragma unroll
    for (int m = 0; m < 4; ++m)
#pragma unroll
        for (int n = 0; n < 4; ++n) acc[m][n] = zz;

    const int srow = tid >> 2;          // 0..63
    const int sbo = (tid & 3) * 8;      // halfs
    const _Float16* gA = F  + (size_t)(lr0 + srow) * KTOT + sbo;
    const _Float16* gB = Wh + (size_t)(o0 + srow) * KTOT + sbo;
    _Float16* lA = As + tid * 8;        // byte off = tid*16 = srow*64 + sbo*2
    _Float16* lB = Bs + tid * 8;

    const int ar = wr + (l & 15), br = wc + (l & 15), ko = (l >> 4) * 8;

    for (int s = 0; s < KTOT / 32; ++s) {
        const int k0 = s * 32;
        gload16(gA + k0, lA);
        gload16(gA + k0 + (size_t)64 * KTOT, lA + 64 * 32);
        gload16(gB + k0, lB);
        gload16(gB + k0 + (size_t)64 * KTOT, lB + 64 * 32);
        __syncthreads();                 // drains vmcnt -> tiles visible
        half8 af[4], bf[4];
#pragma unroll
        for (int m = 0; m < 4; ++m) af[m] = *(const half8*)&As[(ar + m * 16) * 32 + ko];
#pragma unroll
        for (int n = 0; n < 4; ++n) bf[n] = *(const half8*)&Bs[(br + n * 16) * 32 + ko];
#pragma unroll
        for (int m = 0; m < 4; ++m)
#pragma unroll
            for (int n = 0; n < 4; ++n)
                acc[m][n] = __builtin_amdgcn_mfma_f32_16x16x32_f16(af[m], bf[n], acc[m][n], 0, 0, 0);
        __syncthreads();                 // all reads done before next overwrite
    }

    const float rs = rsp[0];
#pragma unroll
    for (int m = 0; m < 4; ++m)
#pragma unroll
        for (int n = 0; n < 4; ++n)
#pragma unroll
            for (int j = 0; j < 4; ++j) {
                const int r = row0 + lr0 + wr + m * 16 + (l >> 4) * 4 + j;
                const int c = o0 + wc + n * 16 + (l & 15);
                float v = acc[m][n][j] + rs * x[(size_t)r * IN_DIM + c];
                float e = __expf(2.f * v);           // tanh = 1 - 2/(e^2v+1)
                out[(size_t)r * OUT_DIM + c] = 1.f - 2.f / (e + 1.f);
            }
}

extern "C" void kernel_launch(void* const* d_in, const int* in_sizes, int n_in,
                              void* d_out, int out_size, void* d_ws, size_t ws_size,
                              hipStream_t stream) {
    const float* x      = (const float*)d_in[0];
    const float* coeffs = (const float*)d_in[1];
    const float* bw     = (const float*)d_in[2];
    const float* gsl    = (const float*)d_in[3];
    const float* gstart = (const float*)d_in[4];
    const float* rs     = (const float*)d_in[5];
    float* out = (float*)d_out;
    float* P   = (float*)d_ws;
    _Float16* Wh = (_Float16*)(P + WS_WH_OFF_F);
    _Float16* F  = (_Float16*)((char*)d_ws + WS_F_OFF_B);

    kan_prep<<<2, 256, 0, stream>>>(gsl, gstart, P);
    kan_packw<<<1024, 256, 0, stream>>>(coeffs, bw, Wh);

    int CH = NBATCH;
    while (CH > 128 && WS_F_OFF_B + (size_t)CH * KTOT * 2 > ws_size) CH >>= 1;
    if (WS_F_OFF_B + (size_t)CH * KTOT * 2 > ws_size) return;  // ws too small: fail loud

    for (int row0 = 0; row0 < NBATCH; row0 += CH) {
        kan_feat<<<2 * (CH / 32), 256, 0, stream>>>(x, P, F, row0);
        kan_gemm<<<(CH / 128) * 4, 256, 0, stream>>>(F, Wh, x, rs, out, row0);
    }
}

// Round 3
// 322.479 us; speedup vs baseline: 1.2773x; 1.0029x over previous
//
#include <hip/hip_runtime.h>
#include <hip/hip_bf16.h>
#include <math.h>

// KAN layer, decoupled: (1) prep grid params, (2) pack weights fp16,
// (3) featurize x -> F[b, i*12+c] fp16 in ws (LDS-staged coalesced stores),
// (4) double-buffered MFMA GEMM  y = tanh(F @ W^T + rs*x)

#define IN_DIM  512
#define OUT_DIM 512
#define FPI     12
#define KTOT    (IN_DIM * FPI)    // 6144
#define NBATCH  16384

// ws layout: P (float, 56 slots x 512 dims, transposed) | Wh fp16 [512][6144]
//          | F fp16 [CH][6144]
#define P_SLOTS     56
#define WS_WH_OFF_F (P_SLOTS * IN_DIM)
#define WS_F_OFF_B  ((size_t)(P_SLOTS * IN_DIM * 4) + (size_t)OUT_DIM * KTOT * 2)

typedef _Float16 half8 __attribute__((ext_vector_type(8)));
typedef float f32x4 __attribute__((ext_vector_type(4)));

__device__ __forceinline__ void gload16(const void* g, void* l) {
    __builtin_amdgcn_global_load_lds((const __attribute__((address_space(1))) void*)g,
                                     (__attribute__((address_space(3))) void*)l, 16, 0, 0);
}

// ---------------- kernel 1: knot positions + inverse denominators ----------
// P slots: t[0..14] | inv1[0..13]@15 | inv2[0..12]@29 | inv3[0..11]@42, P[slot*512+dim]
__global__ void kan_prep(const float* __restrict__ gsl, const float* __restrict__ gstart,
                         float* __restrict__ P) {
    int i = blockIdx.x * 256 + threadIdx.x;
    if (i >= IN_DIM) return;
    float t[15];
    float a = gstart[i];
    t[0] = a;
#pragma unroll
    for (int m = 0; m < 14; ++m) {
        float z = gsl[i * 14 + m];
        a += fmaxf(z, 0.f) + log1pf(__expf(-fabsf(z)));   // softplus, stable
        t[m + 1] = a;
    }
#pragma unroll
    for (int m = 0; m < 15; ++m) P[m * IN_DIM + i] = t[m];
#pragma unroll
    for (int m = 0; m < 14; ++m) { float d = t[m+1] - t[m]; P[(15+m)*IN_DIM + i] = 1.f / ((d == 0.f) ? 1.f : d); }
#pragma unroll
    for (int m = 0; m < 13; ++m) { float d = t[m+2] - t[m]; P[(29+m)*IN_DIM + i] = 1.f / ((d == 0.f) ? 1.f : d); }
#pragma unroll
    for (int m = 0; m < 12; ++m) { float d = t[m+3] - t[m]; P[(42+m)*IN_DIM + i] = 1.f / ((d == 0.f) ? 1.f : d); }
}

// ---------------- kernel 2: pack [coeffs | base_weight] to fp16 ------------
__global__ void kan_packw(const float* __restrict__ coeffs, const float* __restrict__ bw,
                          _Float16* __restrict__ Wh) {
    int idx = blockIdx.x * 256 + threadIdx.x;   // idx = o*512 + i
    const float* src = coeffs + (size_t)idx * 11;
    union { _Float16 h[12]; float2 f2[3]; } u;
#pragma unroll
    for (int c = 0; c < 11; ++c) u.h[c] = (_Float16)src[c];
    u.h[11] = (_Float16)bw[idx];
    float2* dst = (float2*)(Wh + (size_t)idx * FPI);
    dst[0] = u.f2[0]; dst[1] = u.f2[1]; dst[2] = u.f2[2];
}

// ---------------- kernel 3: featurize, LDS-staged coalesced output ---------
// block: 256 threads = 256 dims (one half of IN_DIM), FR rows; dense Cox-de Boor.
#define FR 8
__launch_bounds__(256)
__global__ void kan_feat(const float* __restrict__ x, const float* __restrict__ P,
                         _Float16* __restrict__ F, int row0) {
    __shared__ __align__(16) _Float16 Ft[FR][3072];   // 48 KB
    const int tid = threadIdx.x;
    const int half = blockIdx.x & 1;
    const int rb = blockIdx.x >> 1;
    const int dim = half * 256 + tid;
    float t[15], i1[14], i2[13], i3[12];
#pragma unroll
    for (int m = 0; m < 15; ++m) t[m]  = P[m * IN_DIM + dim];
#pragma unroll
    for (int m = 0; m < 14; ++m) i1[m] = P[(15 + m) * IN_DIM + dim];
#pragma unroll
    for (int m = 0; m < 13; ++m) i2[m] = P[(29 + m) * IN_DIM + dim];
#pragma unroll
    for (int m = 0; m < 12; ++m) i3[m] = P[(42 + m) * IN_DIM + dim];
    const int r0 = row0 + rb * FR;
#pragma unroll 2
    for (int r = 0; r < FR; ++r) {
        const float xv = x[(size_t)(r0 + r) * IN_DIM + dim];
        float d[15];
#pragma unroll
        for (int m = 0; m < 15; ++m) d[m] = xv - t[m];
        float b[14];
#pragma unroll
        for (int m = 0; m < 14; ++m) b[m] = (xv >= t[m] && xv < t[m + 1]) ? 1.f : 0.f;
#pragma unroll
        for (int m = 0; m < 13; ++m) b[m] = (d[m] * i1[m]) * b[m] + ((-d[m + 2]) * i1[m + 1]) * b[m + 1];
#pragma unroll
        for (int m = 0; m < 12; ++m) b[m] = (d[m] * i2[m]) * b[m] + ((-d[m + 3]) * i2[m + 1]) * b[m + 1];
#pragma unroll
        for (int m = 0; m < 11; ++m) b[m] = (d[m] * i3[m]) * b[m] + ((-d[m + 4]) * i3[m + 1]) * b[m + 1];
        const float sil = xv / (1.f + __expf(-xv));
        union { _Float16 h[12]; float2 f2[3]; } u;
#pragma unroll
        for (int c = 0; c < 11; ++c) u.h[c] = (_Float16)b[c];
        u.h[11] = (_Float16)sil;
        float2* dst = (float2*)&Ft[r][tid * FPI];   // 24B @ 8B-aligned
        dst[0] = u.f2[0]; dst[1] = u.f2[1]; dst[2] = u.f2[2];
    }
    __syncthreads();
    // coalesced write-out: FR rows x 3072 halfs; 16B/lane contiguous runs
#pragma unroll
    for (int rd = 0; rd < 12; ++rd) {
        const int ci = rd * 256 + tid;              // 16B-chunk index, 384/row
        const int row = ci / 384;
        const int off = (ci - row * 384) * 8;
        float4 v = *(const float4*)&Ft[row][off];
        *(float4*)(F + (size_t)(r0 + row) * KTOT + half * 3072 + off) = v;
    }
}

// ---------------- kernel 4: GEMM, double-buffered prefetch -----------------
#define NS (KTOT / 32)   // 192 K-steps
__launch_bounds__(256, 2)
__global__ void kan_gemm(const _Float16* __restrict__ F, const _Float16* __restrict__ Wh,
                         const float* __restrict__ x, const float* __restrict__ rsp,
                         float* __restrict__ out, int row0) {
    __shared__ _Float16 As[2][128 * 32];
    __shared__ _Float16 Bs[2][128 * 32];
    int bid = blockIdx.x;
    const int nwg = gridDim.x;
    if ((nwg & 7) == 0) bid = (bid & 7) * (nwg >> 3) + (bid >> 3);  // XCD swizzle
    const int rt = bid >> 2, ct = bid & 3;
    const int lr0 = rt * 128, o0 = ct * 128;
    const int tid = threadIdx.x, l = tid & 63, w = tid >> 6;
    const int wr = (w >> 1) * 64, wc = (w & 1) * 64;

    f32x4 acc[4][4];
    const f32x4 zz = {0.f, 0.f, 0.f, 0.f};
#pragma unroll
    for (int m = 0; m < 4; ++m)
#pragma unroll
        for (int n = 0; n < 4; ++n) acc[m][n] = zz;

    const int srow = tid >> 2;          // 0..63
    const int sbo = (tid & 3) * 8;      // halfs
    const _Float16* gA = F  + (size_t)(lr0 + srow) * KTOT + sbo;
    const _Float16* gB = Wh + (size_t)(o0 + srow) * KTOT + sbo;

    const int ar = wr + (l & 15), br = wc + (l & 15), ko = (l >> 4) * 8;

    // prologue: stage step 0 into buffer 0
    {
        gload16(gA, &As[0][tid * 8]);
        gload16(gA + (size_t)64 * KTOT, &As[0][64 * 32 + tid * 8]);
        gload16(gB, &Bs[0][tid * 8]);
        gload16(gB + (size_t)64 * KTOT, &Bs[0][64 * 32 + tid * 8]);
    }
    __syncthreads();

    int cur = 0;
    for (int s = 0; s < NS; ++s) {
        if (s + 1 < NS) {               // issue next-tile loads into other buffer
            const int k1 = (s + 1) * 32;
            const int nb = cur ^ 1;
            gload16(gA + k1, &As[nb][tid * 8]);
            gload16(gA + k1 + (size_t)64 * KTOT, &As[nb][64 * 32 + tid * 8]);
            gload16(gB + k1, &Bs[nb][tid * 8]);
            gload16(gB + k1 + (size_t)64 * KTOT, &Bs[nb][64 * 32 + tid * 8]);
        }
        half8 af[4], bf[4];
#pragma unroll
        for (int m = 0; m < 4; ++m) af[m] = *(const half8*)&As[cur][(ar + m * 16) * 32 + ko];
#pragma unroll
        for (int n = 0; n < 4; ++n) bf[n] = *(const half8*)&Bs[cur][(br + n * 16) * 32 + ko];
#pragma unroll
        for (int m = 0; m < 4; ++m)
#pragma unroll
            for (int n = 0; n < 4; ++n)
                acc[m][n] = __builtin_amdgcn_mfma_f32_16x16x32_f16(af[m], bf[n], acc[m][n], 0, 0, 0);
        __syncthreads();                // drains vmcnt (next tile ready) + read-safety
        cur ^= 1;
    }

    const float rs = rsp[0];
#pragma unroll
    for (int m = 0; m < 4; ++m)
#pragma unroll
        for (int n = 0; n < 4; ++n)
#pragma unroll
            for (int j = 0; j < 4; ++j) {
                const int r = row0 + lr0 + wr + m * 16 + (l >> 4) * 4 + j;
                const int c = o0 + wc + n * 16 + (l & 15);
                float v = acc[m][n][j] + rs * x[(size_t)r * IN_DIM + c];
                float e = __expf(2.f * v);           // tanh = 1 - 2/(e^2v+1)
                out[(size_t)r * OUT_DIM + c] = 1.f - 2.f / (e + 1.f);
            }
}

extern "C" void kernel_launch(void* const* d_in, const int* in_sizes, int n_in,
                              void* d_out, int out_size, void* d_ws, size_t ws_size,
                              hipStream_t stream) {
    const float* x      = (const float*)d_in[0];
    const float* coeffs = (const float*)d_in[1];
    const float* bw     = (const float*)d_in[2];
    const float* gsl    = (const float*)d_in[3];
    const float* gstart = (const float*)d_in[4];
    const float* rs     = (const float*)d_in[5];
    float* out = (float*)d_out;
    float* P   = (float*)d_ws;
    _Float16* Wh = (_Float16*)(P + WS_WH_OFF_F);
    _Float16* F  = (_Float16*)((char*)d_ws + WS_F_OFF_B);

    kan_prep<<<2, 256, 0, stream>>>(gsl, gstart, P);
    kan_packw<<<1024, 256, 0, stream>>>(coeffs, bw, Wh);

    int CH = NBATCH;
    while (CH > 128 && WS_F_OFF_B + (size_t)CH * KTOT * 2 > ws_size) CH >>= 1;
    if (WS_F_OFF_B + (size_t)CH * KTOT * 2 > ws_size) return;  // ws too small: fail loud

    for (int row0 = 0; row0 < NBATCH; row0 += CH) {
        kan_feat<<<2 * (CH / FR), 256, 0, stream>>>(x, P, F, row0);
        kan_gemm<<<(CH / 128) * 4, 256, 0, stream>>>(F, Wh, x, rs, out, row0);
    }
}